// Round 9
// baseline (437.419 us; speedup 1.0000x reference)
//
#include <hip/hip_runtime.h>

#define NN 50000
#define NE 800000
#define EBLKC 3125   // (NE+255)/256 degree blocks in fused kernel
#define GBLKC 782    // (NN+63)/64 GEMM tiles

// ---- bf16 helpers (manual RNE; values are finite) --------------------------
__device__ inline unsigned short f2bf(float f) {
    unsigned u = __float_as_uint(f);
    unsigned r = (u + 0x7FFFu + ((u >> 16) & 1u)) >> 16;
    return (unsigned short)r;
}
__device__ inline float bf2f_lo(unsigned u) { return __uint_as_float(u << 16); }
__device__ inline float bf2f_hi(unsigned u) { return __uint_as_float(u & 0xFFFF0000u); }

// ---- X = rowscale(A) @ W, register-blocked 64x64 tile (device body) --------
// 256 threads -> 64 rows x 64 cols, 4x4 acc/thread. A staged transposed in
// LDS (pitch 68); W row-major. Row index clamped (always-in-bounds loads);
// stores guarded. OUT_BF16 packs to bf16.
template <int K, bool OUT_BF16>
__device__ __forceinline__ void proj_body(
    const float* __restrict__ A, int lda,
    const float* __restrict__ W,   // K x 64, row-major
    const float* __restrict__ scale,
    void* __restrict__ Xout,
    float* sAT, float* sW, int tile) {
    constexpr int KC = 64;
    constexpr int NCHUNK = K / KC;
    float acc[4][4] = {};

    const int t = threadIdx.x;
    const int tx = t & 15;
    const int ty = t >> 4;
    const int row0 = tile * 64;

    const int srow = t & 63;
    const int f0 = t >> 6;
    int grow = row0 + srow;
    if (grow > NN - 1) grow = NN - 1;
    const float* arow = A + (size_t)grow * lda;

    for (int kc = 0; kc < NCHUNK; ++kc) {
#pragma unroll
        for (int it = 0; it < 4; ++it) {
            int k = (f0 + it * 4) * 4;
            float4 a4 = *reinterpret_cast<const float4*>(arow + kc * KC + k);
            sAT[(k + 0) * 68 + srow] = a4.x;
            sAT[(k + 1) * 68 + srow] = a4.y;
            sAT[(k + 2) * 68 + srow] = a4.z;
            sAT[(k + 3) * 68 + srow] = a4.w;
        }
        {
            const float4* wsrc = reinterpret_cast<const float4*>(W + (size_t)kc * KC * 64);
            float4* wdst = reinterpret_cast<float4*>(sW);
#pragma unroll
            for (int it = 0; it < 4; ++it) wdst[t + it * 256] = wsrc[t + it * 256];
        }
        __syncthreads();
#pragma unroll 8
        for (int k = 0; k < KC; ++k) {
            float4 av = *reinterpret_cast<const float4*>(&sAT[k * 68 + ty * 4]);
            float4 wv = *reinterpret_cast<const float4*>(&sW[k * 64 + tx * 4]);
            acc[0][0] = fmaf(av.x, wv.x, acc[0][0]);
            acc[0][1] = fmaf(av.x, wv.y, acc[0][1]);
            acc[0][2] = fmaf(av.x, wv.z, acc[0][2]);
            acc[0][3] = fmaf(av.x, wv.w, acc[0][3]);
            acc[1][0] = fmaf(av.y, wv.x, acc[1][0]);
            acc[1][1] = fmaf(av.y, wv.y, acc[1][1]);
            acc[1][2] = fmaf(av.y, wv.z, acc[1][2]);
            acc[1][3] = fmaf(av.y, wv.w, acc[1][3]);
            acc[2][0] = fmaf(av.z, wv.x, acc[2][0]);
            acc[2][1] = fmaf(av.z, wv.y, acc[2][1]);
            acc[2][2] = fmaf(av.z, wv.z, acc[2][2]);
            acc[2][3] = fmaf(av.z, wv.w, acc[2][3]);
            acc[3][0] = fmaf(av.w, wv.x, acc[3][0]);
            acc[3][1] = fmaf(av.w, wv.y, acc[3][1]);
            acc[3][2] = fmaf(av.w, wv.z, acc[3][2]);
            acc[3][3] = fmaf(av.w, wv.w, acc[3][3]);
        }
        __syncthreads();
    }
#pragma unroll
    for (int i = 0; i < 4; ++i) {
        int r = row0 + ty * 4 + i;
        if (r < NN) {
            float s = scale ? scale[r] : 1.0f;
            float4 o = {acc[i][0] * s, acc[i][1] * s, acc[i][2] * s, acc[i][3] * s};
            if (OUT_BF16) {
                ushort4 h = {f2bf(o.x), f2bf(o.y), f2bf(o.z), f2bf(o.w)};
                *reinterpret_cast<ushort4*>((unsigned short*)Xout + (size_t)r * 64 + tx * 4) = h;
            } else {
                *reinterpret_cast<float4*>((float*)Xout + (size_t)r * 64 + tx * 4) = o;
            }
        }
    }
}

template <int K, bool OUT_BF16>
__global__ __launch_bounds__(256) void proj_kernel(
    const float* __restrict__ A, int lda, const float* __restrict__ W,
    const float* __restrict__ scale, void* __restrict__ Xout) {
    __shared__ float smem[64 * 68 + 64 * 64];
    proj_body<K, OUT_BF16>(A, lda, W, scale, Xout, smem, smem + 64 * 68, blockIdx.x);
}

// ---- fused: degree+cursor atomics (blocks < EBLKC) || proj0 unscaled -------
// Degree path is memory-side-atomic-rate bound with ~0.3% VALU use; the
// K=256 GEMM (independent of degrees) fills those latency bubbles.
__global__ __launch_bounds__(256) void fused_degree_proj0_kernel(
    const int* __restrict__ src, const int* __restrict__ dst,
    int* __restrict__ dout_cnt, int* __restrict__ cursor, int* __restrict__ epos,
    const float* __restrict__ feat, const float* __restrict__ W0,
    void* __restrict__ Xout) {
    __shared__ float smem[64 * 68 + 64 * 64];
    if (blockIdx.x < EBLKC) {
        int e = blockIdx.x * 256 + threadIdx.x;
        if (e < NE) {
            atomicAdd(&dout_cnt[src[e]], 1);
            epos[e] = atomicAdd(&cursor[dst[e]], 1);  // cursor doubles as din_cnt
        }
    } else {
        proj_body<256, true>(feat, 256, W0, nullptr, Xout, smem, smem + 64 * 68,
                             blockIdx.x - EBLKC);
    }
}

// ---- scale X (bf16, in place): X[n,:] *= dout_is[n] ------------------------
__global__ void scale_x_kernel(unsigned* __restrict__ Xq, const float* __restrict__ dout_is) {
    int t = blockIdx.x * 256 + threadIdx.x;   // one uint4 (8 bf16) per thread
    if (t >= NN * 8) return;
    float s = dout_is[t >> 3];
    uint4 v = reinterpret_cast<uint4*>(Xq)[t];
    unsigned* p = &v.x;
#pragma unroll
    for (int j = 0; j < 4; ++j) {
        float lo = bf2f_lo(p[j]) * s;
        float hi = bf2f_hi(p[j]) * s;
        p[j] = (unsigned)f2bf(lo) | ((unsigned)f2bf(hi) << 16);
    }
    reinterpret_cast<uint4*>(Xq)[t] = v;
}

// ---- scan helpers ----------------------------------------------------------
__device__ inline int wave_incl_scan(int v) {
    int lane = threadIdx.x & 63;
#pragma unroll
    for (int off = 1; off < 64; off <<= 1) {
        int t = __shfl_up(v, off, 64);
        if (lane >= off) v += t;
    }
    return v;
}

__global__ void scan_local_kernel(const int* __restrict__ din_cnt,
                                  int* __restrict__ row_start,
                                  int* __restrict__ partials) {
    __shared__ int wsum[4];
    int i = blockIdx.x * 256 + threadIdx.x;
    int v = (i < NN) ? din_cnt[i] : 0;
    int lane = threadIdx.x & 63, wid = threadIdx.x >> 6;
    int incl = wave_incl_scan(v);
    if (lane == 63) wsum[wid] = incl;
    __syncthreads();
    if (threadIdx.x == 0) {
        int s = 0;
        for (int w = 0; w < 4; ++w) { int t = wsum[w]; wsum[w] = s; s += t; }
        partials[blockIdx.x] = s;
    }
    __syncthreads();
    if (i < NN) row_start[i] = incl - v + wsum[wid];
}

__global__ void scan_partials_kernel(int* __restrict__ partials, int nparts,
                                     int* __restrict__ row_start) {
    __shared__ int wsum[4];
    int v = (threadIdx.x < nparts) ? partials[threadIdx.x] : 0;
    int lane = threadIdx.x & 63, wid = threadIdx.x >> 6;
    int incl = wave_incl_scan(v);
    if (lane == 63) wsum[wid] = incl;
    __syncthreads();
    if (threadIdx.x == 0) {
        int s = 0;
        for (int w = 0; w < 4; ++w) { int t = wsum[w]; wsum[w] = s; s += t; }
        row_start[NN] = NE;
    }
    __syncthreads();
    if (threadIdx.x < nparts) partials[threadIdx.x] = incl - v + wsum[wid];
}

__global__ void scan_add_norm_kernel(int* __restrict__ row_start, const int* __restrict__ partials,
                                     const int* __restrict__ dout_cnt, const int* __restrict__ din_cnt,
                                     float* __restrict__ dout_is, float* __restrict__ din_is) {
    int i = blockIdx.x * 256 + threadIdx.x;
    if (i < NN) {
        row_start[i] += partials[blockIdx.x];
        dout_is[i] = rsqrtf(fmaxf((float)dout_cnt[i], 1.0f));
        din_is[i]  = rsqrtf(fmaxf((float)din_cnt[i], 1.0f));
    }
}

__global__ void csr_fill_kernel(const int* __restrict__ src, const int* __restrict__ dst,
                                const int* __restrict__ row_start, const int* __restrict__ epos,
                                int* __restrict__ csr_src) {
    int e = blockIdx.x * 256 + threadIdx.x;
    if (e < NE) csr_src[row_start[dst[e]] + epos[e]] = src[e];
}

// ---- pull aggregation: 8 neighbor rows per load instruction ----------------
// One wave per dst row. g = lane>>3 (neighbor group), q = lane&7 (uint4 within
// row: cols 8q..8q+7). Each uint4 load = 16 B/lane, one instruction covers 8
// different 128B bf16 rows. f64 partials (order-insensitive vs atomic slot
// order) reduced with 3 shfl_xor rounds; group 0 stores 2x float4.
__global__ __launch_bounds__(256) void gather8_bf16_kernel(
    const int* __restrict__ row_start, const int* __restrict__ csr_src,
    const unsigned* __restrict__ Xq, const float* __restrict__ din_is,
    const float* __restrict__ b, float* __restrict__ out,
    int ldo, int coff, int relu) {
    int n = blockIdx.x * 4 + (threadIdx.x >> 6);
    if (n >= NN) return;
    int lane = threadIdx.x & 63;
    int g = lane >> 3;
    int q = lane & 7;
    const size_t qo = (size_t)q * 4;
    int s0 = row_start[n], s1 = row_start[n + 1];
    double a0 = 0, a1 = 0, a2 = 0, a3 = 0, a4 = 0, a5 = 0, a6 = 0, a7 = 0;
#define ACC8(v)                                                    \
    a0 += (double)bf2f_lo(v.x); a1 += (double)bf2f_hi(v.x);        \
    a2 += (double)bf2f_lo(v.y); a3 += (double)bf2f_hi(v.y);        \
    a4 += (double)bf2f_lo(v.z); a5 += (double)bf2f_hi(v.z);        \
    a6 += (double)bf2f_lo(v.w); a7 += (double)bf2f_hi(v.w);
    int i = s0;
    for (; i + 16 <= s1; i += 16) {
        int ia = csr_src[i + g];
        int ib = csr_src[i + 8 + g];
        uint4 va = *reinterpret_cast<const uint4*>(Xq + (size_t)ia * 32 + qo);
        uint4 vb = *reinterpret_cast<const uint4*>(Xq + (size_t)ib * 32 + qo);
        ACC8(va); ACC8(vb);
    }
    for (; i + 8 <= s1; i += 8) {
        int ia = csr_src[i + g];
        uint4 va = *reinterpret_cast<const uint4*>(Xq + (size_t)ia * 32 + qo);
        ACC8(va);
    }
    if (i + g < s1) {
        int ia = csr_src[i + g];
        uint4 va = *reinterpret_cast<const uint4*>(Xq + (size_t)ia * 32 + qo);
        ACC8(va);
    }
#undef ACC8
#define RED(x) x += __shfl_xor(x, 8, 64); x += __shfl_xor(x, 16, 64); x += __shfl_xor(x, 32, 64);
    RED(a0) RED(a1) RED(a2) RED(a3) RED(a4) RED(a5) RED(a6) RED(a7)
#undef RED
    if (g == 0) {
        int c0 = q * 8;
        float r[8] = {(float)a0, (float)a1, (float)a2, (float)a3,
                      (float)a4, (float)a5, (float)a6, (float)a7};
        if (relu) {
            float di = din_is[n];
#pragma unroll
            for (int j = 0; j < 8; ++j) r[j] = fmaxf(fmaf(r[j], di, b[c0 + j]), 0.0f);
        } else {
#pragma unroll
            for (int j = 0; j < 8; ++j) r[j] += b[c0 + j];
        }
        float4 o0 = {r[0], r[1], r[2], r[3]};
        float4 o1 = {r[4], r[5], r[6], r[7]};
        float* p = out + (size_t)n * ldo + coff + c0;
        *reinterpret_cast<float4*>(p) = o0;
        *reinterpret_cast<float4*>(p + 4) = o1;
    }
}

extern "C" void kernel_launch(void* const* d_in, const int* in_sizes, int n_in,
                              void* d_out, int out_size, void* d_ws, size_t ws_size,
                              hipStream_t stream) {
    const float* feat  = (const float*)d_in[0];
    const int*   src   = (const int*)d_in[1];
    const int*   dst   = (const int*)d_in[2];
    const float* W[4]  = {(const float*)d_in[3], (const float*)d_in[5],
                          (const float*)d_in[7], (const float*)d_in[9]};
    const float* b[4]  = {(const float*)d_in[4], (const float*)d_in[6],
                          (const float*)d_in[8], (const float*)d_in[10]};
    const float* W_mlp = (const float*)d_in[11];
    const float* b_mlp = (const float*)d_in[12];
    float* out = (float*)d_out;

    // workspace layout:
    // C [NN*256 f]  (head transiently reused: dout_cnt [NN i] | cursor [NN i]
    //               | epos [NE i] — all dead before gather-0 writes C)
    // X [NN*64 f]   (bf16/uint views alias the same region)
    // dout_is [NN f] | din_is [NN f] |
    // row_start [NN+1 i] | partials [256 i] | csr_src [NE i]
    float* C        = (float*)d_ws;
    int*   dout_cnt = (int*)d_ws;            // NN
    int*   cursor   = dout_cnt + NN;         // NN (doubles as din_cnt)
    int*   epos     = cursor + NN;           // NE
    float* X        = C + (size_t)NN * 256;
    unsigned short* Xh = (unsigned short*)X;
    unsigned*       Xq = (unsigned*)X;
    float* dout_is  = X + (size_t)NN * 64;
    float* din_is   = dout_is + NN;
    int*   row_start = (int*)(din_is + NN);
    int*   partials  = row_start + NN + 1;
    int*   csr_src   = partials + 256;

    const int NBLK = (NN + 255) / 256;   // 196
    const int EBLK = (NE + 255) / 256;   // 3125
    const int SBLK = (NN * 8 + 255) / 256;  // 1563 (scale_x)

    // zero dout_cnt + cursor (contiguous)
    hipMemsetAsync(dout_cnt, 0, 2 * NN * sizeof(int), stream);

    // degree+cursor atomics overlapped with the K=256 proj0 (unscaled bf16 X)
    fused_degree_proj0_kernel<<<EBLKC + GBLKC, 256, 0, stream>>>(
        src, dst, dout_cnt, cursor, epos, feat, W[0], Xh);

    // row_start = exscan(cursor); fill is atomic-free
    scan_local_kernel<<<NBLK, 256, 0, stream>>>(cursor, row_start, partials);
    scan_partials_kernel<<<1, 256, 0, stream>>>(partials, NBLK, row_start);
    scan_add_norm_kernel<<<NBLK, 256, 0, stream>>>(row_start, partials, dout_cnt, cursor,
                                                   dout_is, din_is);
    csr_fill_kernel<<<EBLK, 256, 0, stream>>>(src, dst, row_start, epos, csr_src);

    // apply dout^{-1/2} row scale to the already-projected layer-0 X
    scale_x_kernel<<<SBLK, 256, 0, stream>>>(Xq, dout_is);

    gather8_bf16_kernel<<<12500, 256, 0, stream>>>(row_start, csr_src, Xq, din_is, b[0], C, 256, 0, 1);

    // layers 1..3 (K = 64), input = previous slice of C — bf16 X (scaled in proj)
    for (int i = 1; i < 4; ++i) {
        proj_kernel<64, true><<<GBLKC, 256, 0, stream>>>(C + (i - 1) * 64, 256, W[i], dout_is, Xh);
        gather8_bf16_kernel<<<12500, 256, 0, stream>>>(row_start, csr_src, Xq, din_is, b[i], C, 256, i * 64, 1);
    }

    // tail: P = C @ W_mlp as bf16 (project BEFORE the neighbor-sum; linear),
    // then out = b_mlp + segment_sum(P[src] -> dst)
    proj_kernel<256, true><<<GBLKC, 256, 0, stream>>>(C, 256, W_mlp, nullptr, Xh);
    gather8_bf16_kernel<<<12500, 256, 0, stream>>>(row_start, csr_src, Xq, nullptr, b_mlp, out, 64, 0, 0);
}

// Round 10
// 418.160 us; speedup vs baseline: 1.0461x; 1.0461x over previous
//
#include <hip/hip_runtime.h>

#define NN 50000
#define NE 800000
#define EBLK 3125    // (NE+255)/256 degree/fill blocks
#define GBLK 782     // (NN+63)/64 GEMM tiles
#define SBLK 1563    // (NN*8+255)/256 scale blocks
#define FUSED_BLOCKS 3910   // interleaved: 3128 degree (3 idle) + 782 proj

// ---- bf16 helpers (manual RNE; values are finite) --------------------------
__device__ inline unsigned short f2bf(float f) {
    unsigned u = __float_as_uint(f);
    unsigned r = (u + 0x7FFFu + ((u >> 16) & 1u)) >> 16;
    return (unsigned short)r;
}
__device__ inline float bf2f_lo(unsigned u) { return __uint_as_float(u << 16); }
__device__ inline float bf2f_hi(unsigned u) { return __uint_as_float(u & 0xFFFF0000u); }

// ---- X = rowscale(A) @ W, register-blocked 64x64 tile (device body) --------
// 256 threads -> 64 rows x 64 cols, 4x4 acc/thread. A staged transposed in
// LDS (pitch 68); W row-major. Row index clamped (always-in-bounds loads);
// stores guarded. OUT_BF16 packs to bf16.
template <int K, bool OUT_BF16>
__device__ __forceinline__ void proj_body(
    const float* __restrict__ A, int lda,
    const float* __restrict__ W,   // K x 64, row-major
    const float* __restrict__ scale,
    void* __restrict__ Xout,
    float* sAT, float* sW, int tile) {
    constexpr int KC = 64;
    constexpr int NCHUNK = K / KC;
    float acc[4][4] = {};

    const int t = threadIdx.x;
    const int tx = t & 15;
    const int ty = t >> 4;
    const int row0 = tile * 64;

    const int srow = t & 63;
    const int f0 = t >> 6;
    int grow = row0 + srow;
    if (grow > NN - 1) grow = NN - 1;
    const float* arow = A + (size_t)grow * lda;

    for (int kc = 0; kc < NCHUNK; ++kc) {
#pragma unroll
        for (int it = 0; it < 4; ++it) {
            int k = (f0 + it * 4) * 4;
            float4 a4 = *reinterpret_cast<const float4*>(arow + kc * KC + k);
            sAT[(k + 0) * 68 + srow] = a4.x;
            sAT[(k + 1) * 68 + srow] = a4.y;
            sAT[(k + 2) * 68 + srow] = a4.z;
            sAT[(k + 3) * 68 + srow] = a4.w;
        }
        {
            const float4* wsrc = reinterpret_cast<const float4*>(W + (size_t)kc * KC * 64);
            float4* wdst = reinterpret_cast<float4*>(sW);
#pragma unroll
            for (int it = 0; it < 4; ++it) wdst[t + it * 256] = wsrc[t + it * 256];
        }
        __syncthreads();
#pragma unroll 8
        for (int k = 0; k < KC; ++k) {
            float4 av = *reinterpret_cast<const float4*>(&sAT[k * 68 + ty * 4]);
            float4 wv = *reinterpret_cast<const float4*>(&sW[k * 64 + tx * 4]);
            acc[0][0] = fmaf(av.x, wv.x, acc[0][0]);
            acc[0][1] = fmaf(av.x, wv.y, acc[0][1]);
            acc[0][2] = fmaf(av.x, wv.z, acc[0][2]);
            acc[0][3] = fmaf(av.x, wv.w, acc[0][3]);
            acc[1][0] = fmaf(av.y, wv.x, acc[1][0]);
            acc[1][1] = fmaf(av.y, wv.y, acc[1][1]);
            acc[1][2] = fmaf(av.y, wv.z, acc[1][2]);
            acc[1][3] = fmaf(av.y, wv.w, acc[1][3]);
            acc[2][0] = fmaf(av.z, wv.x, acc[2][0]);
            acc[2][1] = fmaf(av.z, wv.y, acc[2][1]);
            acc[2][2] = fmaf(av.z, wv.z, acc[2][2]);
            acc[2][3] = fmaf(av.z, wv.w, acc[2][3]);
            acc[3][0] = fmaf(av.w, wv.x, acc[3][0]);
            acc[3][1] = fmaf(av.w, wv.y, acc[3][1]);
            acc[3][2] = fmaf(av.w, wv.z, acc[3][2]);
            acc[3][3] = fmaf(av.w, wv.w, acc[3][3]);
        }
        __syncthreads();
    }
#pragma unroll
    for (int i = 0; i < 4; ++i) {
        int r = row0 + ty * 4 + i;
        if (r < NN) {
            float s = scale ? scale[r] : 1.0f;
            float4 o = {acc[i][0] * s, acc[i][1] * s, acc[i][2] * s, acc[i][3] * s};
            if (OUT_BF16) {
                ushort4 h = {f2bf(o.x), f2bf(o.y), f2bf(o.z), f2bf(o.w)};
                *reinterpret_cast<ushort4*>((unsigned short*)Xout + (size_t)r * 64 + tx * 4) = h;
            } else {
                *reinterpret_cast<float4*>((float*)Xout + (size_t)r * 64 + tx * 4) = o;
            }
        }
    }
}

template <int K, bool OUT_BF16>
__global__ __launch_bounds__(256) void proj_kernel(
    const float* __restrict__ A, int lda, const float* __restrict__ W,
    const float* __restrict__ scale, void* __restrict__ Xout) {
    __shared__ float smem[64 * 68 + 64 * 64];
    proj_body<K, OUT_BF16>(A, lda, W, scale, Xout, smem, smem + 64 * 68, blockIdx.x);
}

// ---- fused: degree+cursor atomics INTERLEAVED with proj0 (unscaled) --------
// Role: blockIdx%5==4 -> proj tile blockIdx/5; else degree block
// idx = blockIdx - (blockIdx+1)/5. Interleaving keeps ~20% GEMM blocks
// resident alongside atomic-latency-bound degree blocks at every point in
// the dispatch (R9's sequential layout ran the two phases serially).
__global__ __launch_bounds__(256) void fused_degree_proj0_kernel(
    const int* __restrict__ src, const int* __restrict__ dst,
    int* __restrict__ dout_cnt, int* __restrict__ cursor, int* __restrict__ epos,
    const float* __restrict__ feat, const float* __restrict__ W0,
    void* __restrict__ Xout) {
    __shared__ float smem[64 * 68 + 64 * 64];
    int bid = blockIdx.x;
    if ((bid % 5) == 4) {
        proj_body<256, true>(feat, 256, W0, nullptr, Xout, smem, smem + 64 * 68, bid / 5);
    } else {
        int dblk = bid - (bid + 1) / 5;
        int e = dblk * 256 + threadIdx.x;
        if (e < NE) {
            atomicAdd(&dout_cnt[src[e]], 1);
            epos[e] = atomicAdd(&cursor[dst[e]], 1);  // cursor doubles as din_cnt
        }
    }
}

// ---- scan helpers ----------------------------------------------------------
__device__ inline int wave_incl_scan(int v) {
    int lane = threadIdx.x & 63;
#pragma unroll
    for (int off = 1; off < 64; off <<= 1) {
        int t = __shfl_up(v, off, 64);
        if (lane >= off) v += t;
    }
    return v;
}

__global__ void scan_local_kernel(const int* __restrict__ din_cnt,
                                  int* __restrict__ row_start,
                                  int* __restrict__ partials) {
    __shared__ int wsum[4];
    int i = blockIdx.x * 256 + threadIdx.x;
    int v = (i < NN) ? din_cnt[i] : 0;
    int lane = threadIdx.x & 63, wid = threadIdx.x >> 6;
    int incl = wave_incl_scan(v);
    if (lane == 63) wsum[wid] = incl;
    __syncthreads();
    if (threadIdx.x == 0) {
        int s = 0;
        for (int w = 0; w < 4; ++w) { int t = wsum[w]; wsum[w] = s; s += t; }
        partials[blockIdx.x] = s;
    }
    __syncthreads();
    if (i < NN) row_start[i] = incl - v + wsum[wid];
}

__global__ void scan_partials_kernel(int* __restrict__ partials, int nparts,
                                     int* __restrict__ row_start) {
    __shared__ int wsum[4];
    int v = (threadIdx.x < nparts) ? partials[threadIdx.x] : 0;
    int lane = threadIdx.x & 63, wid = threadIdx.x >> 6;
    int incl = wave_incl_scan(v);
    if (lane == 63) wsum[wid] = incl;
    __syncthreads();
    if (threadIdx.x == 0) {
        int s = 0;
        for (int w = 0; w < 4; ++w) { int t = wsum[w]; wsum[w] = s; s += t; }
        row_start[NN] = NE;
    }
    __syncthreads();
    if (threadIdx.x < nparts) partials[threadIdx.x] = incl - v + wsum[wid];
}

__global__ void scan_add_norm_kernel(int* __restrict__ row_start, const int* __restrict__ partials,
                                     const int* __restrict__ dout_cnt, const int* __restrict__ din_cnt,
                                     float* __restrict__ dout_is, float* __restrict__ din_is) {
    int i = blockIdx.x * 256 + threadIdx.x;
    if (i < NN) {
        row_start[i] += partials[blockIdx.x];
        dout_is[i] = rsqrtf(fmaxf((float)dout_cnt[i], 1.0f));
        din_is[i]  = rsqrtf(fmaxf((float)din_cnt[i], 1.0f));
    }
}

// ---- fused: CSR fill (atomic-free) || X *= dout_is row-scale ---------------
// Blocks < EBLK scatter csr_src; remaining SBLK blocks apply the dout^{-1/2}
// scale to the already-projected layer-0 bf16 X (dout_is ready after
// scan_add_norm). Both are latency-bound; fusing removes one dispatch.
__global__ void csr_fill_scale_kernel(const int* __restrict__ src, const int* __restrict__ dst,
                                      const int* __restrict__ row_start, const int* __restrict__ epos,
                                      int* __restrict__ csr_src,
                                      unsigned* __restrict__ Xq, const float* __restrict__ dout_is) {
    int bid = blockIdx.x;
    if (bid < EBLK) {
        int e = bid * 256 + threadIdx.x;
        if (e < NE) csr_src[row_start[dst[e]] + epos[e]] = src[e];
    } else {
        int t = (bid - EBLK) * 256 + threadIdx.x;  // one uint4 (8 bf16) per thread
        if (t < NN * 8) {
            float s = dout_is[t >> 3];
            uint4 v = reinterpret_cast<uint4*>(Xq)[t];
            unsigned* p = &v.x;
#pragma unroll
            for (int j = 0; j < 4; ++j) {
                float lo = bf2f_lo(p[j]) * s;
                float hi = bf2f_hi(p[j]) * s;
                p[j] = (unsigned)f2bf(lo) | ((unsigned)f2bf(hi) << 16);
            }
            reinterpret_cast<uint4*>(Xq)[t] = v;
        }
    }
}

// ---- pull aggregation: 8 neighbor rows per load instruction ----------------
// One wave per dst row. g = lane>>3 (neighbor group), q = lane&7 (uint4 within
// row: cols 8q..8q+7). Each uint4 load = 16 B/lane, one instruction covers 8
// different 128B bf16 rows. f64 partials (order-insensitive vs atomic slot
// order) reduced with 3 shfl_xor rounds; group 0 stores 2x float4.
__global__ __launch_bounds__(256) void gather8_bf16_kernel(
    const int* __restrict__ row_start, const int* __restrict__ csr_src,
    const unsigned* __restrict__ Xq, const float* __restrict__ din_is,
    const float* __restrict__ b, float* __restrict__ out,
    int ldo, int coff, int relu) {
    int n = blockIdx.x * 4 + (threadIdx.x >> 6);
    if (n >= NN) return;
    int lane = threadIdx.x & 63;
    int g = lane >> 3;
    int q = lane & 7;
    const size_t qo = (size_t)q * 4;
    int s0 = row_start[n], s1 = row_start[n + 1];
    double a0 = 0, a1 = 0, a2 = 0, a3 = 0, a4 = 0, a5 = 0, a6 = 0, a7 = 0;
#define ACC8(v)                                                    \
    a0 += (double)bf2f_lo(v.x); a1 += (double)bf2f_hi(v.x);        \
    a2 += (double)bf2f_lo(v.y); a3 += (double)bf2f_hi(v.y);        \
    a4 += (double)bf2f_lo(v.z); a5 += (double)bf2f_hi(v.z);        \
    a6 += (double)bf2f_lo(v.w); a7 += (double)bf2f_hi(v.w);
    int i = s0;
    for (; i + 16 <= s1; i += 16) {
        int ia = csr_src[i + g];
        int ib = csr_src[i + 8 + g];
        uint4 va = *reinterpret_cast<const uint4*>(Xq + (size_t)ia * 32 + qo);
        uint4 vb = *reinterpret_cast<const uint4*>(Xq + (size_t)ib * 32 + qo);
        ACC8(va); ACC8(vb);
    }
    for (; i + 8 <= s1; i += 8) {
        int ia = csr_src[i + g];
        uint4 va = *reinterpret_cast<const uint4*>(Xq + (size_t)ia * 32 + qo);
        ACC8(va);
    }
    if (i + g < s1) {
        int ia = csr_src[i + g];
        uint4 va = *reinterpret_cast<const uint4*>(Xq + (size_t)ia * 32 + qo);
        ACC8(va);
    }
#undef ACC8
#define RED(x) x += __shfl_xor(x, 8, 64); x += __shfl_xor(x, 16, 64); x += __shfl_xor(x, 32, 64);
    RED(a0) RED(a1) RED(a2) RED(a3) RED(a4) RED(a5) RED(a6) RED(a7)
#undef RED
    if (g == 0) {
        int c0 = q * 8;
        float r[8] = {(float)a0, (float)a1, (float)a2, (float)a3,
                      (float)a4, (float)a5, (float)a6, (float)a7};
        if (relu) {
            float di = din_is[n];
#pragma unroll
            for (int j = 0; j < 8; ++j) r[j] = fmaxf(fmaf(r[j], di, b[c0 + j]), 0.0f);
        } else {
#pragma unroll
            for (int j = 0; j < 8; ++j) r[j] += b[c0 + j];
        }
        float4 o0 = {r[0], r[1], r[2], r[3]};
        float4 o1 = {r[4], r[5], r[6], r[7]};
        float* p = out + (size_t)n * ldo + coff + c0;
        *reinterpret_cast<float4*>(p) = o0;
        *reinterpret_cast<float4*>(p + 4) = o1;
    }
}

extern "C" void kernel_launch(void* const* d_in, const int* in_sizes, int n_in,
                              void* d_out, int out_size, void* d_ws, size_t ws_size,
                              hipStream_t stream) {
    const float* feat  = (const float*)d_in[0];
    const int*   src   = (const int*)d_in[1];
    const int*   dst   = (const int*)d_in[2];
    const float* W[4]  = {(const float*)d_in[3], (const float*)d_in[5],
                          (const float*)d_in[7], (const float*)d_in[9]};
    const float* b[4]  = {(const float*)d_in[4], (const float*)d_in[6],
                          (const float*)d_in[8], (const float*)d_in[10]};
    const float* W_mlp = (const float*)d_in[11];
    const float* b_mlp = (const float*)d_in[12];
    float* out = (float*)d_out;

    // workspace layout:
    // C [NN*256 f]  (head transiently reused: dout_cnt [NN i] | cursor [NN i]
    //               | epos [NE i] — all dead before gather-0 writes C)
    // X [NN*64 f]   (bf16/uint views alias the same region)
    // dout_is [NN f] | din_is [NN f] |
    // row_start [NN+1 i] | partials [256 i] | csr_src [NE i]
    float* C        = (float*)d_ws;
    int*   dout_cnt = (int*)d_ws;            // NN
    int*   cursor   = dout_cnt + NN;         // NN (doubles as din_cnt)
    int*   epos     = cursor + NN;           // NE
    float* X        = C + (size_t)NN * 256;
    unsigned short* Xh = (unsigned short*)X;
    unsigned*       Xq = (unsigned*)X;
    float* dout_is  = X + (size_t)NN * 64;
    float* din_is   = dout_is + NN;
    int*   row_start = (int*)(din_is + NN);
    int*   partials  = row_start + NN + 1;
    int*   csr_src   = partials + 256;

    const int NBLK = (NN + 255) / 256;   // 196

    // zero dout_cnt + cursor (contiguous)
    hipMemsetAsync(dout_cnt, 0, 2 * NN * sizeof(int), stream);

    // degree+cursor atomics interleaved with the K=256 proj0 (unscaled bf16 X)
    fused_degree_proj0_kernel<<<FUSED_BLOCKS, 256, 0, stream>>>(
        src, dst, dout_cnt, cursor, epos, feat, W[0], Xh);

    // row_start = exscan(cursor)
    scan_local_kernel<<<NBLK, 256, 0, stream>>>(cursor, row_start, partials);
    scan_partials_kernel<<<1, 256, 0, stream>>>(partials, NBLK, row_start);
    scan_add_norm_kernel<<<NBLK, 256, 0, stream>>>(row_start, partials, dout_cnt, cursor,
                                                   dout_is, din_is);

    // atomic-free CSR fill || apply dout^{-1/2} row scale to layer-0 X
    csr_fill_scale_kernel<<<EBLK + SBLK, 256, 0, stream>>>(src, dst, row_start, epos,
                                                           csr_src, Xq, dout_is);

    gather8_bf16_kernel<<<12500, 256, 0, stream>>>(row_start, csr_src, Xq, din_is, b[0], C, 256, 0, 1);

    // layers 1..3 (K = 64), input = previous slice of C — bf16 X (scaled in proj)
    for (int i = 1; i < 4; ++i) {
        proj_kernel<64, true><<<GBLK, 256, 0, stream>>>(C + (i - 1) * 64, 256, W[i], dout_is, Xh);
        gather8_bf16_kernel<<<12500, 256, 0, stream>>>(row_start, csr_src, Xq, din_is, b[i], C, 256, i * 64, 1);
    }

    // tail: P = C @ W_mlp as bf16 (project BEFORE the neighbor-sum; linear),
    // then out = b_mlp + segment_sum(P[src] -> dst)
    proj_kernel<256, true><<<GBLK, 256, 0, stream>>>(C, 256, W_mlp, nullptr, Xh);
    gather8_bf16_kernel<<<12500, 256, 0, stream>>>(row_start, csr_src, Xq, nullptr, b_mlp, out, 64, 0, 0);
}